// Round 2
// baseline (569.600 us; speedup 1.0000x reference)
//
#include <hip/hip_runtime.h>
#include <hip/hip_bf16.h>
#include <stdint.h>

#define D_DIM 256
#define KBIG 768

typedef __attribute__((ext_vector_type(8))) short bf16x8_t;
typedef __attribute__((ext_vector_type(4))) float f32x4_t;

__device__ __forceinline__ float bf2f(uint16_t u) {
    union { uint32_t i; float f; } v; v.i = ((uint32_t)u) << 16; return v.f;
}
__device__ __forceinline__ float blo(uint32_t w) {
    union { uint32_t i; float f; } v; v.i = w << 16; return v.f;
}
__device__ __forceinline__ float bhi(uint32_t w) {
    union { uint32_t i; float f; } v; v.i = w & 0xFFFF0000u; return v.f;
}
__device__ __forceinline__ uint16_t f2bf(float f) {
    union { float f; uint32_t i; } v; v.f = f;
    uint32_t x = v.i;
    uint32_t r = (x + 0x7FFFu + ((x >> 16) & 1u)) >> 16;
    return (uint16_t)r;
}
__device__ __forceinline__ uint32_t pack2(float a, float b) {
    return (uint32_t)f2bf(a) | ((uint32_t)f2bf(b) << 16);
}
__device__ __forceinline__ float loadv(const void* base, int f, size_t idx) {
    return f ? ((const float*)base)[idx] : bf2f(((const uint16_t*)base)[idx]);
}
__device__ __forceinline__ float fast_tanh(float x) {
    // tanh(x) = 1 - 2/(exp(2x)+1); exp2-based, ~1e-6 abs error, saturates correctly
    float t = __builtin_amdgcn_exp2f(x * 2.8853900817779268f);
    return 1.f - 2.f * __builtin_amdgcn_rcpf(t + 1.f);
}

// async global->LDS, 16B per lane; LDS dest = wave-uniform base + lane*16
__device__ __forceinline__ void gll16(const uint16_t* g, uint16_t* l) {
    __builtin_amdgcn_global_load_lds(
        (const __attribute__((address_space(1))) uint32_t*)(const void*)g,
        (__attribute__((address_space(3))) uint32_t*)(void*)l, 16, 0, 0);
}

// ---- dtype detect: low-16 halves of u32 words; bf16 exponents cluster in [100,140]
__global__ void k_detect(const uint32_t* __restrict__ xw, int* __restrict__ flag) {
    __shared__ int cnt[256];
    int t = threadIdx.x;
    int c = 0;
    for (int j = 0; j < 16; j++) {
        uint32_t w = xw[(size_t)(t * 16 + j) * 797];
        uint32_t e = (w >> 7) & 0xFF;
        if (e >= 100 && e <= 140) c++;
    }
    cnt[t] = c;
    __syncthreads();
    for (int off = 128; off > 0; off >>= 1) {
        if (t < off) cnt[t] += cnt[t + off];
        __syncthreads();
    }
    if (t == 0) flag[0] = (cnt[0] < 2048) ? 1 : 0;   // 1 = f32, 0 = bf16
}

// ---- cast to canonical bf16 (8 elems/thread). skip_bf: don't write when already bf16.
__global__ __launch_bounds__(256) void k_cast(const void* __restrict__ src,
                                              uint16_t* __restrict__ dst,
                                              int nvec, const int* __restrict__ flagp,
                                              int skip_bf) {
    int f = *flagp;
    int i = blockIdx.x * 256 + threadIdx.x;
    if (i >= nvec) return;
    size_t base = (size_t)i * 8;
    if (f) {
        const float* s = (const float*)src + base;
        float4 a = *(const float4*)s;
        float4 b = *(const float4*)(s + 4);
        uint4 o;
        o.x = (uint32_t)f2bf(a.x) | ((uint32_t)f2bf(a.y) << 16);
        o.y = (uint32_t)f2bf(a.z) | ((uint32_t)f2bf(a.w) << 16);
        o.z = (uint32_t)f2bf(b.x) | ((uint32_t)f2bf(b.y) << 16);
        o.w = (uint32_t)f2bf(b.z) | ((uint32_t)f2bf(b.w) << 16);
        *(uint4*)(dst + base) = o;
    } else {
        if (skip_bf) return;
        *(uint4*)(dst + base) = *(const uint4*)((const uint16_t*)src + base);
    }
}

// ---- transpose weights (dual dtype) into canonical bf16
__global__ void k_transpose(const void* __restrict__ w0, const void* __restrict__ w1,
                            const void* __restrict__ w2, const void* __restrict__ w3,
                            const int* __restrict__ flagp,
                            uint16_t* __restrict__ bt_big, uint16_t* __restrict__ bt_rel) {
    __shared__ uint16_t tile[32][33];
    int f = *flagp;
    int mat = blockIdx.z;
    const void* src = mat == 0 ? w0 : mat == 1 ? w1 : mat == 2 ? w2 : w3;
    int k0 = blockIdx.y * 32, n0 = blockIdx.x * 32;
    int tx = threadIdx.x, ty = threadIdx.y;
    tile[ty][tx] = f2bf(loadv(src, f, (size_t)(k0 + ty) * D_DIM + n0 + tx));
    __syncthreads();
    int n = n0 + ty, k = k0 + tx;
    if (mat < 3) bt_big[(size_t)n * KBIG + mat * D_DIM + k] = tile[tx][ty];
    else         bt_rel[(size_t)n * D_DIM + k] = tile[tx][ty];
}

// ---- cvec[c] = bias[c] - (loop_rel @ w_loop)[c]; 1 wave per output column
__global__ void k_cvec(const void* __restrict__ loop_rel, const void* __restrict__ w_loop,
                       const void* __restrict__ bias, const int* __restrict__ flagp,
                       float* __restrict__ cvec) {
    int f = *flagp;
    int c = blockIdx.x;
    int lane = threadIdx.x;                 // 64 lanes
    float s = 0.f;
#pragma unroll
    for (int kk = 0; kk < 4; kk++) {
        int k = kk * 64 + lane;
        s += loadv(loop_rel, f, k) * loadv(w_loop, f, (size_t)k * D_DIM + c);
    }
#pragma unroll
    for (int off = 32; off; off >>= 1) s += __shfl_down(s, off);
    if (lane == 0) cvec[c] = loadv(bias, f, c) - s;
}

// ---- degree histogram (total + in-half)
__global__ void k_hist(const int* __restrict__ rows, int E, int half,
                       int* __restrict__ deg, int* __restrict__ deg_in) {
    int i = blockIdx.x * blockDim.x + threadIdx.x;
    if (i < E) {
        int r = rows[i];
        atomicAdd(&deg[r], 1);
        if (i < half) atomicAdd(&deg_in[r], 1);
    }
}

// ---- scan stage A
__global__ void k_scan_a(const int* __restrict__ deg, int N, int* __restrict__ row_start,
                         int* __restrict__ blk_sum, float* __restrict__ dinv) {
    __shared__ int s[1024];
    int t = threadIdx.x;
    int i = blockIdx.x * 1024 + t;
    int v = (i < N) ? deg[i] : 0;
    if (i < N) dinv[i] = v > 0 ? rsqrtf((float)v) : 0.f;
    s[t] = v;
    __syncthreads();
    for (int off = 1; off < 1024; off <<= 1) {
        int add = (t >= off) ? s[t - off] : 0;
        __syncthreads();
        s[t] += add;
        __syncthreads();
    }
    if (i < N) row_start[i] = s[t] - v;
    if (t == 1023) blk_sum[blockIdx.x] = s[1023];
}

// ---- scan stage B (nb <= 128)
__global__ void k_scan_b(int* __restrict__ blk_sum, int nb) {
    __shared__ int s[128];
    int t = threadIdx.x;
    int v = (t < nb) ? blk_sum[t] : 0;
    s[t] = v;
    __syncthreads();
    for (int off = 1; off < 128; off <<= 1) {
        int add = (t >= off) ? s[t - off] : 0;
        __syncthreads();
        s[t] += add;
        __syncthreads();
    }
    if (t < nb) blk_sum[t] = s[t] - v;
}

// ---- scan stage C: finalize row_start; seed both segment cursors
// cursor_in[node]  = row_start[node]                (in-edges fill front)
// cursor_out[node] = row_start[node] + deg_in[node] (out-edges fill back)
__global__ void k_scan_c(int* __restrict__ row_start, const int* __restrict__ blk_sum,
                         const int* __restrict__ deg_in,
                         int N, int E, int* __restrict__ cur_in, int* __restrict__ cur_out) {
    int i = blockIdx.x * 1024 + threadIdx.x;
    if (i < N) {
        int v = row_start[i] + blk_sum[blockIdx.x];
        row_start[i] = v;
        cur_in[i] = v;
        cur_out[i] = v + deg_in[i];
    }
    if (i == 0) row_start[N] = E;
}

// ---- fill CSR records: col | et<<17, segment-sorted (in-edges then out-edges)
__global__ void k_fill(const int* __restrict__ ei, const int* __restrict__ et, int E, int half,
                       int* __restrict__ cur_in, int* __restrict__ cur_out,
                       uint32_t* __restrict__ csr) {
    int e = blockIdx.x * blockDim.x + threadIdx.x;
    if (e >= E) return;
    int r_ = ei[e];
    int c_ = ei[E + e];
    int t_ = et[e];
    uint32_t rec = (uint32_t)c_ | ((uint32_t)t_ << 17);
    int pos = (e < half) ? atomicAdd(&cur_in[r_], 1) : atomicAdd(&cur_out[r_], 1);
    csr[pos] = rec;
}

// ---- per-node pre-matmul aggregation over segment-sorted CSR.
// Phase 1: both wave halves stride the in-segment [s, mid) (even/odd edges),
// shfl_xor(32) combine, half 0 stores s_in. Phase 2: same over [mid, e),
// half 1 stores s_out. No flag decode, no divergent accumulate, 8 live accs.
__global__ __launch_bounds__(256) void k_agg(
    const uint32_t* __restrict__ csr, const int* __restrict__ row_start,
    const int* __restrict__ deg_in, const float* __restrict__ dinv,
    const void* __restrict__ x_raw, const uint16_t* __restrict__ x_bf,
    const uint16_t* __restrict__ r_bf, const int* __restrict__ flagp,
    uint16_t* __restrict__ s_in, uint16_t* __restrict__ s_out, int N) {
    const uint16_t* xs = (*flagp) ? x_bf : (const uint16_t*)x_raw;
    int node = blockIdx.x * 4 + (threadIdx.x >> 6);
    int lane = threadIdx.x & 63;
    if (node >= N) return;
    int half = lane >> 5;
    int co = (lane & 31) * 8;
    int s = row_start[node], e = row_start[node + 1];
    int mid = s + deg_in[node];
    float di = dinv[node];
    float a[8];

    // ---- phase 1: in-edges
#pragma unroll
    for (int k = 0; k < 8; k++) a[k] = 0.f;
    for (int j = s + half; j < mid; j += 2) {
        uint32_t rec = csr[j];
        int c = rec & 131071;
        int et = rec >> 17;
        float nrm = di * dinv[c];
        uint4 xv = *(const uint4*)(xs + ((size_t)c << 8) + co);
        uint4 rv = *(const uint4*)(r_bf + ((size_t)et << 8) + co);
        a[0] = fmaf(blo(xv.x) - blo(rv.x), nrm, a[0]);
        a[1] = fmaf(bhi(xv.x) - bhi(rv.x), nrm, a[1]);
        a[2] = fmaf(blo(xv.y) - blo(rv.y), nrm, a[2]);
        a[3] = fmaf(bhi(xv.y) - bhi(rv.y), nrm, a[3]);
        a[4] = fmaf(blo(xv.z) - blo(rv.z), nrm, a[4]);
        a[5] = fmaf(bhi(xv.z) - bhi(rv.z), nrm, a[5]);
        a[6] = fmaf(blo(xv.w) - blo(rv.w), nrm, a[6]);
        a[7] = fmaf(bhi(xv.w) - bhi(rv.w), nrm, a[7]);
    }
#pragma unroll
    for (int k = 0; k < 8; k++) a[k] += __shfl_xor(a[k], 32);
    if (half == 0) {
        uint4 o;
        o.x = pack2(a[0], a[1]); o.y = pack2(a[2], a[3]);
        o.z = pack2(a[4], a[5]); o.w = pack2(a[6], a[7]);
        *(uint4*)(s_in + (size_t)node * D_DIM + co) = o;
    }

    // ---- phase 2: out-edges
#pragma unroll
    for (int k = 0; k < 8; k++) a[k] = 0.f;
    for (int j = mid + half; j < e; j += 2) {
        uint32_t rec = csr[j];
        int c = rec & 131071;
        int et = rec >> 17;
        float nrm = di * dinv[c];
        uint4 xv = *(const uint4*)(xs + ((size_t)c << 8) + co);
        uint4 rv = *(const uint4*)(r_bf + ((size_t)et << 8) + co);
        a[0] = fmaf(blo(xv.x) - blo(rv.x), nrm, a[0]);
        a[1] = fmaf(bhi(xv.x) - bhi(rv.x), nrm, a[1]);
        a[2] = fmaf(blo(xv.y) - blo(rv.y), nrm, a[2]);
        a[3] = fmaf(bhi(xv.y) - bhi(rv.y), nrm, a[3]);
        a[4] = fmaf(blo(xv.z) - blo(rv.z), nrm, a[4]);
        a[5] = fmaf(bhi(xv.z) - bhi(rv.z), nrm, a[5]);
        a[6] = fmaf(blo(xv.w) - blo(rv.w), nrm, a[6]);
        a[7] = fmaf(bhi(xv.w) - bhi(rv.w), nrm, a[7]);
    }
#pragma unroll
    for (int k = 0; k < 8; k++) a[k] += __shfl_xor(a[k], 32);
    if (half == 1) {
        uint4 o;
        o.x = pack2(a[0], a[1]); o.y = pack2(a[2], a[3]);
        o.z = pack2(a[4], a[5]); o.w = pack2(a[6], a[7]);
        *(uint4*)(s_out + (size_t)node * D_DIM + co) = o;
    }
}

// ---- MFMA GEMM: out[M,256] = [a0|a1|a2][M,ktot] @ bt (+ addvec)
// 512 threads = 8 waves of 64x64 tiles over a 128x256 block tile. BN=256 full
// width -> block owns all columns of its rows -> in-place out==a1 is safe.
// global_load_lds staging (16B/lane) into unpadded LDS rows of 64B with chunk
// swizzle pos = chunk ^ ((row>>1)&3) -> conflict-free ds_read_b128 frag reads.
// Optional fused BatchNorm statistics epilogue (bn_sum/bn_sq non-null):
// per-column sum/sumsq reduced via shfl(quad) -> LDS -> 1 global atomic/col/block.
__global__ __launch_bounds__(512) void k_gemm(
    const uint16_t* a0, const uint16_t* a1,
    const uint16_t* a2, const uint16_t* a2alt, const int* __restrict__ flagp,
    int M, const uint16_t* __restrict__ bt, int bstride, int ktot,
    const float* __restrict__ addvec, uint16_t* out,
    float* __restrict__ bn_sum, float* __restrict__ bn_sq) {
    __shared__ uint16_t As[128 * 32];
    __shared__ uint16_t Bs[256 * 32];
    const uint16_t* a2s = (*flagp) ? a2 : a2alt;
    int t = threadIdx.x;
    int mbase = blockIdx.x * 128;
    int wave = t >> 6, lane = t & 63;
    int wm = (wave >> 2) * 64, wn = (wave & 3) * 64;
    int quad = lane >> 4, l15 = lane & 15;

    // staging precompute (loop-invariant): 1 A-inst + 2 B-insts per wave
    int roff = lane >> 2, cidx = lane & 3;
    int arowL = wave * 16 + roff;                     // LDS row 0..127
    int achk = cidx ^ ((arowL >> 1) & 3);
    int agrow = mbase + arowL; if (agrow > M - 1) agrow = M - 1;
    size_t aoff = (size_t)agrow * D_DIM + achk * 8;
    uint16_t* aldsb = &As[(wave * 16) * 32];

    int browL0 = wave * 32 + roff;                    // LDS rows 0..255
    int browL1 = browL0 + 16;
    int bchk0 = cidx ^ ((browL0 >> 1) & 3);
    int bchk1 = cidx ^ ((browL1 >> 1) & 3);
    size_t boff0 = (size_t)browL0 * bstride + bchk0 * 8;
    size_t boff1 = (size_t)browL1 * bstride + bchk1 * 8;
    uint16_t* bldsb0 = &Bs[(wave * 32) * 32];
    uint16_t* bldsb1 = &Bs[(wave * 32 + 16) * 32];

    // fragment LDS offsets (loop-invariant, swizzled)
    int afo[4], bfo[4];
#pragma unroll
    for (int im = 0; im < 4; im++) {
        int row = wm + im * 16 + l15;
        afo[im] = row * 32 + (quad ^ ((row >> 1) & 3)) * 8;
    }
#pragma unroll
    for (int in = 0; in < 4; in++) {
        int row = wn + in * 16 + l15;
        bfo[in] = row * 32 + (quad ^ ((row >> 1) & 3)) * 8;
    }

    f32x4_t acc[4][4];
#pragma unroll
    for (int i = 0; i < 4; i++)
#pragma unroll
        for (int j = 0; j < 4; j++) acc[i][j] = (f32x4_t){0.f, 0.f, 0.f, 0.f};

    for (int kt = 0; kt < ktot; kt += 32) {
        const uint16_t* asec = (kt < 256) ? a0 : (kt < 512 ? a1 : a2s);
        int klocal = kt & 255;
        gll16(asec + aoff + klocal, aldsb);
        gll16(bt + boff0 + kt, bldsb0);
        gll16(bt + boff1 + kt, bldsb1);
        __syncthreads();
        bf16x8_t af[4], bfr[4];
#pragma unroll
        for (int im = 0; im < 4; im++) af[im] = *(const bf16x8_t*)(&As[afo[im]]);
#pragma unroll
        for (int in = 0; in < 4; in++) bfr[in] = *(const bf16x8_t*)(&Bs[bfo[in]]);
#pragma unroll
        for (int im = 0; im < 4; im++)
#pragma unroll
            for (int in = 0; in < 4; in++)
                acc[im][in] = __builtin_amdgcn_mfma_f32_16x16x32_bf16(af[im], bfr[in], acc[im][in], 0, 0, 0);
        __syncthreads();
    }

    float s4[4] = {0.f, 0.f, 0.f, 0.f};
    float q4[4] = {0.f, 0.f, 0.f, 0.f};
#pragma unroll
    for (int im = 0; im < 4; im++) {
#pragma unroll
        for (int in = 0; in < 4; in++) {
            int gn = wn + in * 16 + l15;
            float av_ = addvec ? addvec[gn] : 0.f;
#pragma unroll
            for (int i2 = 0; i2 < 4; i2++) {
                int gm = mbase + wm + im * 16 + quad * 4 + i2;
                if (gm < M) {
                    float val = acc[im][in][i2] + av_;
                    out[(size_t)gm * D_DIM + gn] = f2bf(val);
                    if (bn_sum) { s4[in] += val; q4[in] += val * val; }
                }
            }
        }
    }
    if (bn_sum) {
        float* sred = (float*)As;          // reuse staging LDS (k-loop done)
        if (t < 256) { sred[t] = 0.f; sred[t + 256] = 0.f; }
        __syncthreads();
#pragma unroll
        for (int in = 0; in < 4; in++) {
            float sv = s4[in], qv = q4[in];
            sv += __shfl_xor(sv, 16); sv += __shfl_xor(sv, 32);
            qv += __shfl_xor(qv, 16); qv += __shfl_xor(qv, 32);
            if (quad == 0) {
                int gn = wn + in * 16 + l15;
                atomicAdd(&sred[gn], sv);
                atomicAdd(&sred[gn + 256], qv);
            }
        }
        __syncthreads();
        if (t < 256) {
            atomicAdd(&bn_sum[t], sred[t]);
            atomicAdd(&bn_sq[t], sred[t + 256]);
        }
    }
}

// ---- BN finalize
__global__ void k_bnfin(const float* __restrict__ bn_sum, const float* __restrict__ bn_sq,
                        const void* __restrict__ gamma, const void* __restrict__ beta,
                        const int* __restrict__ flagp,
                        int N, float* __restrict__ scale, float* __restrict__ shift) {
    int f = *flagp;
    int c = threadIdx.x;
    float inv_n = 1.f / (float)N;
    float mean = bn_sum[c] * inv_n;
    float var = bn_sq[c] * inv_n - mean * mean;
    float sc = loadv(gamma, f, c) * rsqrtf(var + 1e-5f);
    scale[c] = sc;
    shift[c] = loadv(beta, f, c) - mean * sc;
}

// ---- final: normalize + tanh, write d_out h region in detected dtype
__global__ __launch_bounds__(256) void k_final(const uint16_t* __restrict__ h_pre,
                                               const float* __restrict__ scale,
                                               const float* __restrict__ shift,
                                               const int* __restrict__ flagp,
                                               void* __restrict__ dout, int total) {
    int f = *flagp;
    int t = blockIdx.x * 256 + threadIdx.x;
    int base = t * 8;
    if (base >= total) return;
    int c0 = base & (D_DIM - 1);
    uint4 v = *(const uint4*)(h_pre + base);
    uint16_t e[8];
    e[0] = (uint16_t)(v.x & 0xFFFF); e[1] = (uint16_t)(v.x >> 16);
    e[2] = (uint16_t)(v.y & 0xFFFF); e[3] = (uint16_t)(v.y >> 16);
    e[4] = (uint16_t)(v.z & 0xFFFF); e[5] = (uint16_t)(v.z >> 16);
    e[6] = (uint16_t)(v.w & 0xFFFF); e[7] = (uint16_t)(v.w >> 16);
    float r[8];
#pragma unroll
    for (int i = 0; i < 8; i++)
        r[i] = fast_tanh(bf2f(e[i]) * scale[c0 + i] + shift[c0 + i]);
    if (f) {
        float* fo = (float*)dout + base;
        float4 o0 = {r[0], r[1], r[2], r[3]};
        float4 o1 = {r[4], r[5], r[6], r[7]};
        *(float4*)fo = o0;
        *(float4*)(fo + 4) = o1;
    } else {
        uint4 o;
        o.x = (uint32_t)f2bf(r[0]) | ((uint32_t)f2bf(r[1]) << 16);
        o.y = (uint32_t)f2bf(r[2]) | ((uint32_t)f2bf(r[3]) << 16);
        o.z = (uint32_t)f2bf(r[4]) | ((uint32_t)f2bf(r[5]) << 16);
        o.w = (uint32_t)f2bf(r[6]) | ((uint32_t)f2bf(r[7]) << 16);
        *(uint4*)((uint16_t*)dout + base) = o;
    }
}

// ---- copy r_out stage -> d_out r region in detected dtype
__global__ void k_store_r(const uint16_t* __restrict__ stage,
                          const int* __restrict__ flagp,
                          void* __restrict__ dout, size_t off, int cnt) {
    int f = *flagp;
    int i = (blockIdx.x * 256 + threadIdx.x) * 4;
    if (i >= cnt) return;
    ushort4 v = *(const ushort4*)(stage + i);
    if (f) {
        float4 o = {bf2f(v.x), bf2f(v.y), bf2f(v.z), bf2f(v.w)};
        *(float4*)((float*)dout + off + i) = o;
    } else {
        *(ushort4*)((uint16_t*)dout + off + i) = v;
    }
}

extern "C" void kernel_launch(void* const* d_in, const int* in_sizes, int n_in,
                              void* d_out, int out_size, void* d_ws, size_t ws_size,
                              hipStream_t stream) {
    const void* x        = d_in[0];
    const void* r        = d_in[1];
    const void* w_in     = d_in[2];
    const void* w_out    = d_in[3];
    const void* w_loop   = d_in[4];
    const void* w_rel    = d_in[5];
    const void* loop_rel = d_in[6];
    const void* bias     = d_in[7];
    const void* bn_gamma = d_in[8];
    const void* bn_beta  = d_in[9];
    const int* edge_index = (const int*)d_in[10];
    const int* edge_type  = (const int*)d_in[11];

    const int N = in_sizes[0] / D_DIM;       // 100000
    const int R = in_sizes[1] / D_DIM;       // 474
    const int E = in_sizes[11];              // 1000000
    const int half = E / 2;

    // ---- workspace carve (~58.5 MB)
    char* p = (char*)d_ws;
    auto alloc = [&](size_t bytes) -> void* {
        void* q = (void*)p;
        p += (bytes + 255) & ~(size_t)255;
        return q;
    };
    uint16_t* s_out   = (uint16_t*)alloc((size_t)N * D_DIM * 2);   // also h_pre (in-place GEMM out)
    uint32_t* csr     = (uint32_t*)alloc((size_t)E * 4);
    uint16_t* bt_big  = (uint16_t*)alloc((size_t)D_DIM * KBIG * 2);
    uint16_t* bt_rel  = (uint16_t*)alloc((size_t)D_DIM * D_DIM * 2);
    uint16_t* r_bf    = (uint16_t*)alloc((size_t)R * D_DIM * 2 + 65536); // slack for OOB-clamped rows
    uint16_t* r_stage = (uint16_t*)alloc((size_t)R * D_DIM * 2);
    int*      deg     = (int*)alloc((size_t)N * 4);
    int*      deg_in  = (int*)alloc((size_t)N * 4);
    int*      rstart  = (int*)alloc((size_t)(N + 1) * 4);
    int*      cursor  = (int*)alloc((size_t)N * 4);
    float*    dinv    = (float*)alloc((size_t)N * 4);
    int*      blksum  = (int*)alloc(128 * 4);
    float*    cvec    = (float*)alloc(D_DIM * 4);
    float*    bn_sum  = (float*)alloc(D_DIM * 4);
    float*    bn_sq   = (float*)alloc(D_DIM * 4);
    float*    bscale  = (float*)alloc(D_DIM * 4);
    float*    bshift  = (float*)alloc(D_DIM * 4);
    int*      dflag   = (int*)alloc(256);

    // cursor_out aliases deg: deg is only read by k_scan_a, which completes
    // before k_scan_c seeds the cursors.
    int* cursor_out = deg;

    // s_in (bf16) lives in d_out[0 .. 51.2MB); x_bf (bf16, only when input is
    // f32) lives in d_out[51.2 .. 102.4MB) -- valid because f32 d_out h region
    // is 102.4MB. When input is bf16, x is used raw and x_bf never touched.
    uint16_t* s_in = (uint16_t*)d_out;
    uint16_t* x_bf = (uint16_t*)d_out + (size_t)N * D_DIM;
    uint16_t* h_pre = s_out;

    hipMemsetAsync(deg, 0, (size_t)N * 4, stream);
    hipMemsetAsync(deg_in, 0, (size_t)N * 4, stream);
    hipMemsetAsync(bn_sum, 0, D_DIM * 4, stream);
    hipMemsetAsync(bn_sq, 0, D_DIM * 4, stream);

    k_detect<<<1, 256, 0, stream>>>((const uint32_t*)x, dflag);
    // canonical bf16 copies
    int xvec = N * D_DIM / 8;
    k_cast<<<(xvec + 255) / 256, 256, 0, stream>>>(x, x_bf, xvec, dflag, /*skip_bf=*/1);
    int rvec = R * D_DIM / 8;
    k_cast<<<(rvec + 255) / 256, 256, 0, stream>>>(r, r_bf, rvec, dflag, /*skip_bf=*/0);
    k_transpose<<<dim3(8, 8, 4), dim3(32, 32), 0, stream>>>(w_in, w_out, w_loop, w_rel,
                                                            dflag, bt_big, bt_rel);
    k_cvec<<<D_DIM, 64, 0, stream>>>(loop_rel, w_loop, bias, dflag, cvec);

    // CSR build (segment-sorted: in-edges before out-edges within each row)
    int eb = (E + 255) / 256;
    k_hist<<<eb, 256, 0, stream>>>(edge_index, E, half, deg, deg_in);
    int nb = (N + 1023) / 1024;
    k_scan_a<<<nb, 1024, 0, stream>>>(deg, N, rstart, blksum, dinv);
    k_scan_b<<<1, 128, 0, stream>>>(blksum, nb);
    k_scan_c<<<nb, 1024, 0, stream>>>(rstart, blksum, deg_in, N, E, cursor, cursor_out);
    k_fill<<<eb, 256, 0, stream>>>(edge_index, edge_type, E, half, cursor, cursor_out, csr);

    // pre-matmul aggregation: s_in -> d_out, s_out -> ws
    k_agg<<<(N + 3) / 4, 256, 0, stream>>>(csr, rstart, deg_in, dinv, x, x_bf, r_bf, dflag,
                                           s_in, s_out, N);

    // h_pre = [s_in | s_out | x] @ [W_in; W_out; W_loop] + cvec (in place over
    // s_out), with fused BN sum/sumsq epilogue
    int gx = (N + 127) / 128;
    k_gemm<<<gx, 512, 0, stream>>>(s_in, s_out, x_bf, (const uint16_t*)x, dflag,
                                   N, bt_big, KBIG, KBIG, cvec, h_pre, bn_sum, bn_sq);
    // r_stage = r @ w_rel (no stats)
    int gr_ = (R + 127) / 128;
    k_gemm<<<gr_, 512, 0, stream>>>(r_bf, r_bf, r_bf, r_bf, dflag,
                                    R, bt_rel, D_DIM, D_DIM, nullptr, r_stage,
                                    nullptr, nullptr);

    // BatchNorm finalize + tanh -> d_out (dtype per flag)
    k_bnfin<<<1, D_DIM, 0, stream>>>(bn_sum, bn_sq, bn_gamma, bn_beta, dflag, N, bscale, bshift);
    int total = N * D_DIM;
    k_final<<<(total / 8 + 255) / 256, 256, 0, stream>>>(h_pre, bscale, bshift, dflag, d_out, total);
    int rcnt = R * D_DIM;
    k_store_r<<<(rcnt / 4 + 255) / 256, 256, 0, stream>>>(r_stage, dflag, d_out, (size_t)N * D_DIM, rcnt);
}

// Round 3
// 537.310 us; speedup vs baseline: 1.0601x; 1.0601x over previous
//
#include <hip/hip_runtime.h>
#include <hip/hip_bf16.h>
#include <stdint.h>

#define D_DIM 256
#define KBIG 768

typedef __attribute__((ext_vector_type(8))) short bf16x8_t;
typedef __attribute__((ext_vector_type(4))) float f32x4_t;
typedef __attribute__((ext_vector_type(2))) float f32x2_t;

__device__ __forceinline__ float bf2f(uint16_t u) {
    union { uint32_t i; float f; } v; v.i = ((uint32_t)u) << 16; return v.f;
}
__device__ __forceinline__ uint16_t f2bf(float f) {
    union { float f; uint32_t i; } v; v.f = f;
    uint32_t x = v.i;
    uint32_t r = (x + 0x7FFFu + ((x >> 16) & 1u)) >> 16;
    return (uint16_t)r;
}
__device__ __forceinline__ uint32_t pack2(float a, float b) {
    return (uint32_t)f2bf(a) | ((uint32_t)f2bf(b) << 16);
}
__device__ __forceinline__ float loadv(const void* base, int f, size_t idx) {
    return f ? ((const float*)base)[idx] : bf2f(((const uint16_t*)base)[idx]);
}
__device__ __forceinline__ float fast_tanh(float x) {
    // tanh(x) = 1 - 2/(exp(2x)+1); exp2-based, ~1e-6 abs error, saturates correctly
    float t = __builtin_amdgcn_exp2f(x * 2.8853900817779268f);
    return 1.f - 2.f * __builtin_amdgcn_rcpf(t + 1.f);
}
// unpack 2 bf16 (one dword) -> packed f32 pair
__device__ __forceinline__ f32x2_t up2(uint32_t w) {
    union { uint32_t u[2]; f32x2_t f; } c;
    c.u[0] = w << 16;
    c.u[1] = w & 0xFFFF0000u;
    return c.f;
}
// packed fma: acc.lo += a.lo*b.lo, acc.hi += a.hi*b.hi
__device__ __forceinline__ void pkfma(f32x2_t& acc, f32x2_t a, f32x2_t b) {
    asm("v_pk_fma_f32 %0, %1, %2, %0" : "+v"(acc) : "v"(a), "v"(b));
}

// async global->LDS, 16B per lane; LDS dest = wave-uniform base + lane*16
__device__ __forceinline__ void gll16(const uint16_t* g, uint16_t* l) {
    __builtin_amdgcn_global_load_lds(
        (const __attribute__((address_space(1))) uint32_t*)(const void*)g,
        (__attribute__((address_space(3))) uint32_t*)(void*)l, 16, 0, 0);
}

// ---- dtype detect: low-16 halves of u32 words; bf16 exponents cluster in [100,140]
__global__ void k_detect(const uint32_t* __restrict__ xw, int* __restrict__ flag) {
    __shared__ int cnt[256];
    int t = threadIdx.x;
    int c = 0;
    for (int j = 0; j < 16; j++) {
        uint32_t w = xw[(size_t)(t * 16 + j) * 797];
        uint32_t e = (w >> 7) & 0xFF;
        if (e >= 100 && e <= 140) c++;
    }
    cnt[t] = c;
    __syncthreads();
    for (int off = 128; off > 0; off >>= 1) {
        if (t < off) cnt[t] += cnt[t + off];
        __syncthreads();
    }
    if (t == 0) flag[0] = (cnt[0] < 2048) ? 1 : 0;   // 1 = f32, 0 = bf16
}

// ---- cast to canonical bf16 (8 elems/thread). skip_bf: don't write when already bf16.
__global__ __launch_bounds__(256) void k_cast(const void* __restrict__ src,
                                              uint16_t* __restrict__ dst,
                                              int nvec, const int* __restrict__ flagp,
                                              int skip_bf) {
    int f = *flagp;
    int i = blockIdx.x * 256 + threadIdx.x;
    if (i >= nvec) return;
    size_t base = (size_t)i * 8;
    if (f) {
        const float* s = (const float*)src + base;
        float4 a = *(const float4*)s;
        float4 b = *(const float4*)(s + 4);
        uint4 o;
        o.x = (uint32_t)f2bf(a.x) | ((uint32_t)f2bf(a.y) << 16);
        o.y = (uint32_t)f2bf(a.z) | ((uint32_t)f2bf(a.w) << 16);
        o.z = (uint32_t)f2bf(b.x) | ((uint32_t)f2bf(b.y) << 16);
        o.w = (uint32_t)f2bf(b.z) | ((uint32_t)f2bf(b.w) << 16);
        *(uint4*)(dst + base) = o;
    } else {
        if (skip_bf) return;
        *(uint4*)(dst + base) = *(const uint4*)((const uint16_t*)src + base);
    }
}

// ---- transpose weights (dual dtype) into canonical bf16
__global__ void k_transpose(const void* __restrict__ w0, const void* __restrict__ w1,
                            const void* __restrict__ w2, const void* __restrict__ w3,
                            const int* __restrict__ flagp,
                            uint16_t* __restrict__ bt_big, uint16_t* __restrict__ bt_rel) {
    __shared__ uint16_t tile[32][33];
    int f = *flagp;
    int mat = blockIdx.z;
    const void* src = mat == 0 ? w0 : mat == 1 ? w1 : mat == 2 ? w2 : w3;
    int k0 = blockIdx.y * 32, n0 = blockIdx.x * 32;
    int tx = threadIdx.x, ty = threadIdx.y;
    tile[ty][tx] = f2bf(loadv(src, f, (size_t)(k0 + ty) * D_DIM + n0 + tx));
    __syncthreads();
    int n = n0 + ty, k = k0 + tx;
    if (mat < 3) bt_big[(size_t)n * KBIG + mat * D_DIM + k] = tile[tx][ty];
    else         bt_rel[(size_t)n * D_DIM + k] = tile[tx][ty];
}

// ---- cvec[c] = bias[c] - (loop_rel @ w_loop)[c]; 1 wave per output column
__global__ void k_cvec(const void* __restrict__ loop_rel, const void* __restrict__ w_loop,
                       const void* __restrict__ bias, const int* __restrict__ flagp,
                       float* __restrict__ cvec) {
    int f = *flagp;
    int c = blockIdx.x;
    int lane = threadIdx.x;                 // 64 lanes
    float s = 0.f;
#pragma unroll
    for (int kk = 0; kk < 4; kk++) {
        int k = kk * 64 + lane;
        s += loadv(loop_rel, f, k) * loadv(w_loop, f, (size_t)k * D_DIM + c);
    }
#pragma unroll
    for (int off = 32; off; off >>= 1) s += __shfl_down(s, off);
    if (lane == 0) cvec[c] = loadv(bias, f, c) - s;
}

// ---- degree histogram, packed: lo 16 = total deg, hi 16 = in-deg (max deg << 65536)
__global__ void k_hist(const int* __restrict__ rows, int E, int half,
                       int* __restrict__ deg) {
    int i = blockIdx.x * blockDim.x + threadIdx.x;
    if (i < E) atomicAdd(&deg[rows[i]], (i < half) ? 0x10001 : 1);
}

// ---- scan stage A (scans total-degree = low 16 bits of packed deg)
__global__ void k_scan_a(const int* __restrict__ deg, int N, int* __restrict__ row_start,
                         int* __restrict__ blk_sum, float* __restrict__ dinv) {
    __shared__ int s[1024];
    int t = threadIdx.x;
    int i = blockIdx.x * 1024 + t;
    int v = (i < N) ? (deg[i] & 0xFFFF) : 0;
    if (i < N) dinv[i] = v > 0 ? rsqrtf((float)v) : 0.f;
    s[t] = v;
    __syncthreads();
    for (int off = 1; off < 1024; off <<= 1) {
        int add = (t >= off) ? s[t - off] : 0;
        __syncthreads();
        s[t] += add;
        __syncthreads();
    }
    if (i < N) row_start[i] = s[t] - v;
    if (t == 1023) blk_sum[blockIdx.x] = s[1023];
}

// ---- scan stage B (nb <= 128)
__global__ void k_scan_b(int* __restrict__ blk_sum, int nb) {
    __shared__ int s[128];
    int t = threadIdx.x;
    int v = (t < nb) ? blk_sum[t] : 0;
    s[t] = v;
    __syncthreads();
    for (int off = 1; off < 128; off <<= 1) {
        int add = (t >= off) ? s[t - off] : 0;
        __syncthreads();
        s[t] += add;
        __syncthreads();
    }
    if (t < nb) blk_sum[t] = s[t] - v;
}

// ---- scan stage C: finalize row_start; seed both segment cursors
__global__ void k_scan_c(int* __restrict__ row_start, const int* __restrict__ blk_sum,
                         const int* __restrict__ degp,
                         int N, int E, int* __restrict__ cur_in, int* __restrict__ cur_out) {
    int i = blockIdx.x * 1024 + threadIdx.x;
    if (i < N) {
        int v = row_start[i] + blk_sum[blockIdx.x];
        row_start[i] = v;
        cur_in[i] = v;
        cur_out[i] = v + (int)(((unsigned)degp[i]) >> 16);
    }
    if (i == 0) row_start[N] = E;
}

// ---- fill CSR records {meta = col<<9 | et, nrm = dinv[row]*dinv[col]},
// segment-sorted (in-edges fill front of row segment, out-edges fill back)
__global__ void k_fill(const int* __restrict__ ei, const int* __restrict__ et, int E, int half,
                       int* __restrict__ cur_in, int* __restrict__ cur_out,
                       const float* __restrict__ dinv, uint2* __restrict__ csr) {
    int e = blockIdx.x * blockDim.x + threadIdx.x;
    if (e >= E) return;
    int r_ = ei[e];
    int c_ = ei[E + e];
    int t_ = et[e];
    float w = dinv[r_] * dinv[c_];
    uint32_t m = ((uint32_t)c_ << 9) | (uint32_t)t_;
    int pos = (e < half) ? atomicAdd(&cur_in[r_], 1) : atomicAdd(&cur_out[r_], 1);
    csr[pos] = make_uint2(m, __float_as_uint(w));
}

// ---- per-node pre-matmul aggregation over segment-sorted rec64 CSR.
// Record carries precomputed nrm -> no dependent dinv gather, no mul.
// meta & ~511 is the x-row BYTE offset (row stride 512B); (meta&511)<<9 the
// r-row byte offset -> single-op address gen with 32-bit voffsets.
// Channel math: packed v_pk_fma_f32 into separate x/r accumulators, one
// subtract per node. Two phases (in/out), each striding 2 edges/wave via
// half-wave split + shfl_xor(32) combine.
__global__ __launch_bounds__(256) void k_agg(
    const uint2* __restrict__ csr, const int* __restrict__ row_start,
    const int* __restrict__ degp,
    const void* __restrict__ x_raw, const uint16_t* __restrict__ x_bf,
    const uint16_t* __restrict__ r_bf, const int* __restrict__ flagp,
    uint16_t* __restrict__ s_in, uint16_t* __restrict__ s_out, int N) {
    const char* xb = (const char*)((*flagp) ? x_bf : (const uint16_t*)x_raw);
    const char* rb = (const char*)r_bf;
    int node = blockIdx.x * 4 + (threadIdx.x >> 6);
    int lane = threadIdx.x & 63;
    if (node >= N) return;
    int half = lane >> 5;
    int cob = (lane & 31) * 16;            // byte offset of this lane's 8 channels
    int s = row_start[node], e = row_start[node + 1];
    int mid = s + (int)(((unsigned)degp[node]) >> 16);

    f32x2_t ax[4], ar[4];
    float a[8];

    // ---- phase 1: in-edges [s, mid)
#pragma unroll
    for (int k = 0; k < 4; k++) { ax[k] = (f32x2_t){0.f, 0.f}; ar[k] = (f32x2_t){0.f, 0.f}; }
    for (int j = s + half; j < mid; j += 2) {
        uint2 rec = csr[j];
        uint32_t m = rec.x;
        float w = __uint_as_float(rec.y);
        uint4 xv = *(const uint4*)(xb + (m & 0xFFFFFE00u) + cob);
        uint4 rv = *(const uint4*)(rb + ((m & 511u) << 9) + cob);
        f32x2_t w2 = {w, w};
        pkfma(ax[0], up2(xv.x), w2); pkfma(ar[0], up2(rv.x), w2);
        pkfma(ax[1], up2(xv.y), w2); pkfma(ar[1], up2(rv.y), w2);
        pkfma(ax[2], up2(xv.z), w2); pkfma(ar[2], up2(rv.z), w2);
        pkfma(ax[3], up2(xv.w), w2); pkfma(ar[3], up2(rv.w), w2);
    }
#pragma unroll
    for (int k = 0; k < 4; k++) { a[2 * k] = ax[k][0] - ar[k][0]; a[2 * k + 1] = ax[k][1] - ar[k][1]; }
#pragma unroll
    for (int k = 0; k < 8; k++) a[k] += __shfl_xor(a[k], 32);
    if (half == 0) {
        uint4 o;
        o.x = pack2(a[0], a[1]); o.y = pack2(a[2], a[3]);
        o.z = pack2(a[4], a[5]); o.w = pack2(a[6], a[7]);
        *(uint4*)(s_in + (size_t)node * D_DIM + (cob >> 1)) = o;
    }

    // ---- phase 2: out-edges [mid, e)
#pragma unroll
    for (int k = 0; k < 4; k++) { ax[k] = (f32x2_t){0.f, 0.f}; ar[k] = (f32x2_t){0.f, 0.f}; }
    for (int j = mid + half; j < e; j += 2) {
        uint2 rec = csr[j];
        uint32_t m = rec.x;
        float w = __uint_as_float(rec.y);
        uint4 xv = *(const uint4*)(xb + (m & 0xFFFFFE00u) + cob);
        uint4 rv = *(const uint4*)(rb + ((m & 511u) << 9) + cob);
        f32x2_t w2 = {w, w};
        pkfma(ax[0], up2(xv.x), w2); pkfma(ar[0], up2(rv.x), w2);
        pkfma(ax[1], up2(xv.y), w2); pkfma(ar[1], up2(rv.y), w2);
        pkfma(ax[2], up2(xv.z), w2); pkfma(ar[2], up2(rv.z), w2);
        pkfma(ax[3], up2(xv.w), w2); pkfma(ar[3], up2(rv.w), w2);
    }
#pragma unroll
    for (int k = 0; k < 4; k++) { a[2 * k] = ax[k][0] - ar[k][0]; a[2 * k + 1] = ax[k][1] - ar[k][1]; }
#pragma unroll
    for (int k = 0; k < 8; k++) a[k] += __shfl_xor(a[k], 32);
    if (half == 1) {
        uint4 o;
        o.x = pack2(a[0], a[1]); o.y = pack2(a[2], a[3]);
        o.z = pack2(a[4], a[5]); o.w = pack2(a[6], a[7]);
        *(uint4*)(s_out + (size_t)node * D_DIM + (cob >> 1)) = o;
    }
}

// ---- MFMA GEMM: out[M,256] = [a0|a1|a2][M,ktot] @ bt (+ addvec)
// 512 threads = 8 waves of 64x64 tiles over a 128x256 block tile. BN=256 full
// width -> block owns all columns of its rows -> in-place out==a1 is safe.
// global_load_lds staging (16B/lane) into unpadded LDS rows of 64B with chunk
// swizzle pos = chunk ^ ((row>>1)&3) -> conflict-free ds_read_b128 frag reads.
// Optional fused BatchNorm statistics epilogue (bn_sum/bn_sq non-null):
// per-column sum/sumsq reduced via shfl(quad) -> LDS -> 1 global atomic/col/block.
__global__ __launch_bounds__(512) void k_gemm(
    const uint16_t* a0, const uint16_t* a1,
    const uint16_t* a2, const uint16_t* a2alt, const int* __restrict__ flagp,
    int M, const uint16_t* __restrict__ bt, int bstride, int ktot,
    const float* __restrict__ addvec, uint16_t* out,
    float* __restrict__ bn_sum, float* __restrict__ bn_sq) {
    __shared__ uint16_t As[128 * 32];
    __shared__ uint16_t Bs[256 * 32];
    const uint16_t* a2s = (*flagp) ? a2 : a2alt;
    int t = threadIdx.x;
    int mbase = blockIdx.x * 128;
    int wave = t >> 6, lane = t & 63;
    int wm = (wave >> 2) * 64, wn = (wave & 3) * 64;
    int quad = lane >> 4, l15 = lane & 15;

    // staging precompute (loop-invariant): 1 A-inst + 2 B-insts per wave
    int roff = lane >> 2, cidx = lane & 3;
    int arowL = wave * 16 + roff;                     // LDS row 0..127
    int achk = cidx ^ ((arowL >> 1) & 3);
    int agrow = mbase + arowL; if (agrow > M - 1) agrow = M - 1;
    size_t aoff = (size_t)agrow * D_DIM + achk * 8;
    uint16_t* aldsb = &As[(wave * 16) * 32];

    int browL0 = wave * 32 + roff;                    // LDS rows 0..255
    int browL1 = browL0 + 16;
    int bchk0 = cidx ^ ((browL0 >> 1) & 3);
    int bchk1 = cidx ^ ((browL1 >> 1) & 3);
    size_t boff0 = (size_t)browL0 * bstride + bchk0 * 8;
    size_t boff1 = (size_t)browL1 * bstride + bchk1 * 8;
    uint16_t* bldsb0 = &Bs[(wave * 32) * 32];
    uint16_t* bldsb1 = &Bs[(wave * 32 + 16) * 32];

    // fragment LDS offsets (loop-invariant, swizzled)
    int afo[4], bfo[4];
#pragma unroll
    for (int im = 0; im < 4; im++) {
        int row = wm + im * 16 + l15;
        afo[im] = row * 32 + (quad ^ ((row >> 1) & 3)) * 8;
    }
#pragma unroll
    for (int in = 0; in < 4; in++) {
        int row = wn + in * 16 + l15;
        bfo[in] = row * 32 + (quad ^ ((row >> 1) & 3)) * 8;
    }

    f32x4_t acc[4][4];
#pragma unroll
    for (int i = 0; i < 4; i++)
#pragma unroll
        for (int j = 0; j < 4; j++) acc[i][j] = (f32x4_t){0.f, 0.f, 0.f, 0.f};

    for (int kt = 0; kt < ktot; kt += 32) {
        const uint16_t* asec = (kt < 256) ? a0 : (kt < 512 ? a1 : a2s);
        int klocal = kt & 255;
        gll16(asec + aoff + klocal, aldsb);
        gll16(bt + boff0 + kt, bldsb0);
        gll16(bt + boff1 + kt, bldsb1);
        __syncthreads();
        bf16x8_t af[4], bfr[4];
#pragma unroll
        for (int im = 0; im < 4; im++) af[im] = *(const bf16x8_t*)(&As[afo[im]]);
#pragma unroll
        for (int in = 0; in < 4; in++) bfr[in] = *(const bf16x8_t*)(&Bs[bfo[in]]);
#pragma unroll
        for (int im = 0; im < 4; im++)
#pragma unroll
            for (int in = 0; in < 4; in++)
                acc[im][in] = __builtin_amdgcn_mfma_f32_16x16x32_bf16(af[im], bfr[in], acc[im][in], 0, 0, 0);
        __syncthreads();
    }

    float s4[4] = {0.f, 0.f, 0.f, 0.f};
    float q4[4] = {0.f, 0.f, 0.f, 0.f};
#pragma unroll
    for (int im = 0; im < 4; im++) {
#pragma unroll
        for (int in = 0; in < 4; in++) {
            int gn = wn + in * 16 + l15;
            float av_ = addvec ? addvec[gn] : 0.f;
#pragma unroll
            for (int i2 = 0; i2 < 4; i2++) {
                int gm = mbase + wm + im * 16 + quad * 4 + i2;
                if (gm < M) {
                    float val = acc[im][in][i2] + av_;
                    out[(size_t)gm * D_DIM + gn] = f2bf(val);
                    if (bn_sum) { s4[in] += val; q4[in] += val * val; }
                }
            }
        }
    }
    if (bn_sum) {
        float* sred = (float*)As;          // reuse staging LDS (k-loop done)
        if (t < 256) { sred[t] = 0.f; sred[t + 256] = 0.f; }
        __syncthreads();
#pragma unroll
        for (int in = 0; in < 4; in++) {
            float sv = s4[in], qv = q4[in];
            sv += __shfl_xor(sv, 16); sv += __shfl_xor(sv, 32);
            qv += __shfl_xor(qv, 16); qv += __shfl_xor(qv, 32);
            if (quad == 0) {
                int gn = wn + in * 16 + l15;
                atomicAdd(&sred[gn], sv);
                atomicAdd(&sred[gn + 256], qv);
            }
        }
        __syncthreads();
        if (t < 256) {
            atomicAdd(&bn_sum[t], sred[t]);
            atomicAdd(&bn_sq[t], sred[t + 256]);
        }
    }
}

// ---- final: BN finalize (per-block, L2-hot inputs) + normalize + tanh,
// write d_out h region in detected dtype
__global__ __launch_bounds__(256) void k_final(const uint16_t* __restrict__ h_pre,
                                               const float* __restrict__ bn_sum,
                                               const float* __restrict__ bn_sq,
                                               const void* __restrict__ gamma,
                                               const void* __restrict__ beta,
                                               const int* __restrict__ flagp,
                                               int N, void* __restrict__ dout, int total) {
    __shared__ float ssc[256], ssh[256];
    int f = *flagp;
    {
        int c = threadIdx.x;
        float inv_n = 1.f / (float)N;
        float mean = bn_sum[c] * inv_n;
        float var = bn_sq[c] * inv_n - mean * mean;
        float sc = loadv(gamma, f, c) * rsqrtf(var + 1e-5f);
        ssc[c] = sc;
        ssh[c] = loadv(beta, f, c) - mean * sc;
    }
    __syncthreads();
    int t = blockIdx.x * 256 + threadIdx.x;
    int base = t * 8;
    if (base >= total) return;
    int c0 = base & (D_DIM - 1);
    uint4 v = *(const uint4*)(h_pre + base);
    uint16_t e[8];
    e[0] = (uint16_t)(v.x & 0xFFFF); e[1] = (uint16_t)(v.x >> 16);
    e[2] = (uint16_t)(v.y & 0xFFFF); e[3] = (uint16_t)(v.y >> 16);
    e[4] = (uint16_t)(v.z & 0xFFFF); e[5] = (uint16_t)(v.z >> 16);
    e[6] = (uint16_t)(v.w & 0xFFFF); e[7] = (uint16_t)(v.w >> 16);
    float r[8];
#pragma unroll
    for (int i = 0; i < 8; i++)
        r[i] = fast_tanh(bf2f(e[i]) * ssc[c0 + i] + ssh[c0 + i]);
    if (f) {
        float* fo = (float*)dout + base;
        float4 o0 = {r[0], r[1], r[2], r[3]};
        float4 o1 = {r[4], r[5], r[6], r[7]};
        *(float4*)fo = o0;
        *(float4*)(fo + 4) = o1;
    } else {
        uint4 o;
        o.x = (uint32_t)f2bf(r[0]) | ((uint32_t)f2bf(r[1]) << 16);
        o.y = (uint32_t)f2bf(r[2]) | ((uint32_t)f2bf(r[3]) << 16);
        o.z = (uint32_t)f2bf(r[4]) | ((uint32_t)f2bf(r[5]) << 16);
        o.w = (uint32_t)f2bf(r[6]) | ((uint32_t)f2bf(r[7]) << 16);
        *(uint4*)((uint16_t*)dout + base) = o;
    }
}

// ---- copy r_out stage -> d_out r region in detected dtype
__global__ void k_store_r(const uint16_t* __restrict__ stage,
                          const int* __restrict__ flagp,
                          void* __restrict__ dout, size_t off, int cnt) {
    int f = *flagp;
    int i = (blockIdx.x * 256 + threadIdx.x) * 4;
    if (i >= cnt) return;
    ushort4 v = *(const ushort4*)(stage + i);
    if (f) {
        float4 o = {bf2f(v.x), bf2f(v.y), bf2f(v.z), bf2f(v.w)};
        *(float4*)((float*)dout + off + i) = o;
    } else {
        *(ushort4*)((uint16_t*)dout + off + i) = v;
    }
}

extern "C" void kernel_launch(void* const* d_in, const int* in_sizes, int n_in,
                              void* d_out, int out_size, void* d_ws, size_t ws_size,
                              hipStream_t stream) {
    const void* x        = d_in[0];
    const void* r        = d_in[1];
    const void* w_in     = d_in[2];
    const void* w_out    = d_in[3];
    const void* w_loop   = d_in[4];
    const void* w_rel    = d_in[5];
    const void* loop_rel = d_in[6];
    const void* bias     = d_in[7];
    const void* bn_gamma = d_in[8];
    const void* bn_beta  = d_in[9];
    const int* edge_index = (const int*)d_in[10];
    const int* edge_type  = (const int*)d_in[11];

    const int N = in_sizes[0] / D_DIM;       // 100000
    const int R = in_sizes[1] / D_DIM;       // 474
    const int E = in_sizes[11];              // 1000000
    const int half = E / 2;

    // ---- workspace carve (~62.3 MB)
    char* p = (char*)d_ws;
    auto alloc = [&](size_t bytes) -> void* {
        void* q = (void*)p;
        p += (bytes + 255) & ~(size_t)255;
        return q;
    };
    uint16_t* s_out   = (uint16_t*)alloc((size_t)N * D_DIM * 2);   // also h_pre (in-place GEMM out)
    uint2*    csr     = (uint2*)alloc((size_t)E * 8);
    uint16_t* bt_big  = (uint16_t*)alloc((size_t)D_DIM * KBIG * 2);
    uint16_t* bt_rel  = (uint16_t*)alloc((size_t)D_DIM * D_DIM * 2);
    uint16_t* r_bf    = (uint16_t*)alloc((size_t)R * D_DIM * 2 + 65536); // slack for OOB-clamped rows
    uint16_t* r_stage = (uint16_t*)alloc((size_t)R * D_DIM * 2);
    int*      deg     = (int*)alloc((size_t)N * 4);   // packed: lo16 total, hi16 in-deg
    int*      rstart  = (int*)alloc((size_t)(N + 1) * 4);
    int*      cursor  = (int*)alloc((size_t)N * 4);
    int*      cursor_out = (int*)alloc((size_t)N * 4);
    float*    dinv    = (float*)alloc((size_t)N * 4);
    int*      blksum  = (int*)alloc(128 * 4);
    float*    cvec    = (float*)alloc(D_DIM * 4);
    float*    bn_sum  = (float*)alloc(D_DIM * 4);
    float*    bn_sq   = (float*)alloc(D_DIM * 4);
    int*      dflag   = (int*)alloc(256);

    // s_in (bf16) lives in d_out[0 .. 51.2MB); x_bf (bf16, only when input is
    // f32) lives in d_out[51.2 .. 102.4MB) -- valid because f32 d_out h region
    // is 102.4MB. When input is bf16, x is used raw and x_bf never touched.
    uint16_t* s_in = (uint16_t*)d_out;
    uint16_t* x_bf = (uint16_t*)d_out + (size_t)N * D_DIM;
    uint16_t* h_pre = s_out;

    hipMemsetAsync(deg, 0, (size_t)N * 4, stream);
    hipMemsetAsync(bn_sum, 0, D_DIM * 4, stream);
    hipMemsetAsync(bn_sq, 0, D_DIM * 4, stream);

    k_detect<<<1, 256, 0, stream>>>((const uint32_t*)x, dflag);
    // canonical bf16 copies
    int xvec = N * D_DIM / 8;
    k_cast<<<(xvec + 255) / 256, 256, 0, stream>>>(x, x_bf, xvec, dflag, /*skip_bf=*/1);
    int rvec = R * D_DIM / 8;
    k_cast<<<(rvec + 255) / 256, 256, 0, stream>>>(r, r_bf, rvec, dflag, /*skip_bf=*/0);
    k_transpose<<<dim3(8, 8, 4), dim3(32, 32), 0, stream>>>(w_in, w_out, w_loop, w_rel,
                                                            dflag, bt_big, bt_rel);
    k_cvec<<<D_DIM, 64, 0, stream>>>(loop_rel, w_loop, bias, dflag, cvec);

    // CSR build (segment-sorted: in-edges before out-edges within each row)
    int eb = (E + 255) / 256;
    k_hist<<<eb, 256, 0, stream>>>(edge_index, E, half, deg);
    int nb = (N + 1023) / 1024;
    k_scan_a<<<nb, 1024, 0, stream>>>(deg, N, rstart, blksum, dinv);
    k_scan_b<<<1, 128, 0, stream>>>(blksum, nb);
    k_scan_c<<<nb, 1024, 0, stream>>>(rstart, blksum, deg, N, E, cursor, cursor_out);
    k_fill<<<eb, 256, 0, stream>>>(edge_index, edge_type, E, half, cursor, cursor_out,
                                   dinv, csr);

    // pre-matmul aggregation: s_in -> d_out, s_out -> ws
    k_agg<<<(N + 3) / 4, 256, 0, stream>>>(csr, rstart, deg, x, x_bf, r_bf, dflag,
                                           s_in, s_out, N);

    // h_pre = [s_in | s_out | x] @ [W_in; W_out; W_loop] + cvec (in place over
    // s_out), with fused BN sum/sumsq epilogue
    int gx = (N + 127) / 128;
    k_gemm<<<gx, 512, 0, stream>>>(s_in, s_out, x_bf, (const uint16_t*)x, dflag,
                                   N, bt_big, KBIG, KBIG, cvec, h_pre, bn_sum, bn_sq);
    // r_stage = r @ w_rel (no stats)
    int gr_ = (R + 127) / 128;
    k_gemm<<<gr_, 512, 0, stream>>>(r_bf, r_bf, r_bf, r_bf, dflag,
                                    R, bt_rel, D_DIM, D_DIM, nullptr, r_stage,
                                    nullptr, nullptr);

    // BN finalize folded into k_final; normalize + tanh -> d_out (dtype per flag)
    int total = N * D_DIM;
    k_final<<<(total / 8 + 255) / 256, 256, 0, stream>>>(h_pre, bn_sum, bn_sq,
                                                         bn_gamma, bn_beta, dflag,
                                                         N, d_out, total);
    int rcnt = R * D_DIM;
    k_store_r<<<(rcnt / 4 + 255) / 256, 256, 0, stream>>>(r_stage, dflag, d_out, (size_t)N * D_DIM, rcnt);
}

// Round 4
// 529.442 us; speedup vs baseline: 1.0758x; 1.0149x over previous
//
#include <hip/hip_runtime.h>
#include <hip/hip_bf16.h>
#include <stdint.h>

#define D_DIM 256
#define KBIG 768

typedef __attribute__((ext_vector_type(8))) short bf16x8_t;
typedef __attribute__((ext_vector_type(4))) float f32x4_t;
typedef __attribute__((ext_vector_type(2))) float f32x2_t;

__device__ __forceinline__ float bf2f(uint16_t u) {
    union { uint32_t i; float f; } v; v.i = ((uint32_t)u) << 16; return v.f;
}
__device__ __forceinline__ uint16_t f2bf(float f) {
    union { float f; uint32_t i; } v; v.f = f;
    uint32_t x = v.i;
    uint32_t r = (x + 0x7FFFu + ((x >> 16) & 1u)) >> 16;
    return (uint16_t)r;
}
__device__ __forceinline__ uint32_t pack2(float a, float b) {
    return (uint32_t)f2bf(a) | ((uint32_t)f2bf(b) << 16);
}
__device__ __forceinline__ float loadv(const void* base, int f, size_t idx) {
    return f ? ((const float*)base)[idx] : bf2f(((const uint16_t*)base)[idx]);
}
__device__ __forceinline__ float fast_tanh(float x) {
    // tanh(x) = 1 - 2/(exp(2x)+1); exp2-based, ~1e-6 abs error, saturates correctly
    float t = __builtin_amdgcn_exp2f(x * 2.8853900817779268f);
    return 1.f - 2.f * __builtin_amdgcn_rcpf(t + 1.f);
}
// unpack 2 bf16 (one dword) -> packed f32 pair
__device__ __forceinline__ f32x2_t up2(uint32_t w) {
    union { uint32_t u[2]; f32x2_t f; } c;
    c.u[0] = w << 16;
    c.u[1] = w & 0xFFFF0000u;
    return c.f;
}
// packed fma: acc.lo += a.lo*b.lo, acc.hi += a.hi*b.hi
__device__ __forceinline__ void pkfma(f32x2_t& acc, f32x2_t a, f32x2_t b) {
    asm("v_pk_fma_f32 %0, %1, %2, %0" : "+v"(acc) : "v"(a), "v"(b));
}

// async global->LDS, 16B per lane; LDS dest = wave-uniform base + lane*16
__device__ __forceinline__ void gll16(const uint16_t* g, uint16_t* l) {
    __builtin_amdgcn_global_load_lds(
        (const __attribute__((address_space(1))) uint32_t*)(const void*)g,
        (__attribute__((address_space(3))) uint32_t*)(void*)l, 16, 0, 0);
}

// ---- dtype detect (1 wave): low-16 halves of u32 words; bf16 exponents
// cluster in [100,140] (~100% hit), f32 mantissa bits ~16% hit.
__global__ void k_detect(const uint32_t* __restrict__ xw, int* __restrict__ flag) {
    int lane = threadIdx.x;                // 64 lanes
    int c = 0;
#pragma unroll
    for (int j = 0; j < 8; j++) {
        uint32_t w = xw[(size_t)(lane * 8 + j) * 6151];
        uint32_t e = (w >> 7) & 0xFF;
        c += (e >= 100 && e <= 140) ? 1 : 0;
    }
#pragma unroll
    for (int off = 32; off; off >>= 1) c += __shfl_down(c, off);
    if (lane == 0) flag[0] = (c < 128) ? 1 : 0;   // 1 = f32, 0 = bf16
}

// ---- cast to canonical bf16 (8 elems/thread). skip_bf: don't write when already bf16.
__global__ __launch_bounds__(256) void k_cast(const void* __restrict__ src,
                                              uint16_t* __restrict__ dst,
                                              int nvec, const int* __restrict__ flagp,
                                              int skip_bf) {
    int f = *flagp;
    int i = blockIdx.x * 256 + threadIdx.x;
    if (i >= nvec) return;
    size_t base = (size_t)i * 8;
    if (f) {
        const float* s = (const float*)src + base;
        float4 a = *(const float4*)s;
        float4 b = *(const float4*)(s + 4);
        uint4 o;
        o.x = (uint32_t)f2bf(a.x) | ((uint32_t)f2bf(a.y) << 16);
        o.y = (uint32_t)f2bf(a.z) | ((uint32_t)f2bf(a.w) << 16);
        o.z = (uint32_t)f2bf(b.x) | ((uint32_t)f2bf(b.y) << 16);
        o.w = (uint32_t)f2bf(b.z) | ((uint32_t)f2bf(b.w) << 16);
        *(uint4*)(dst + base) = o;
    } else {
        if (skip_bf) return;
        *(uint4*)(dst + base) = *(const uint4*)((const uint16_t*)src + base);
    }
}

// ---- transpose weights (dual dtype) into canonical bf16
__global__ void k_transpose(const void* __restrict__ w0, const void* __restrict__ w1,
                            const void* __restrict__ w2, const void* __restrict__ w3,
                            const int* __restrict__ flagp,
                            uint16_t* __restrict__ bt_big, uint16_t* __restrict__ bt_rel) {
    __shared__ uint16_t tile[32][33];
    int f = *flagp;
    int mat = blockIdx.z;
    const void* src = mat == 0 ? w0 : mat == 1 ? w1 : mat == 2 ? w2 : w3;
    int k0 = blockIdx.y * 32, n0 = blockIdx.x * 32;
    int tx = threadIdx.x, ty = threadIdx.y;
    tile[ty][tx] = f2bf(loadv(src, f, (size_t)(k0 + ty) * D_DIM + n0 + tx));
    __syncthreads();
    int n = n0 + ty, k = k0 + tx;
    if (mat < 3) bt_big[(size_t)n * KBIG + mat * D_DIM + k] = tile[tx][ty];
    else         bt_rel[(size_t)n * D_DIM + k] = tile[tx][ty];
}

// ---- cvec[c] = bias[c] - (loop_rel @ w_loop)[c]; 1 wave per output column
__global__ void k_cvec(const void* __restrict__ loop_rel, const void* __restrict__ w_loop,
                       const void* __restrict__ bias, const int* __restrict__ flagp,
                       float* __restrict__ cvec) {
    int f = *flagp;
    int c = blockIdx.x;
    int lane = threadIdx.x;                 // 64 lanes
    float s = 0.f;
#pragma unroll
    for (int kk = 0; kk < 4; kk++) {
        int k = kk * 64 + lane;
        s += loadv(loop_rel, f, k) * loadv(w_loop, f, (size_t)k * D_DIM + c);
    }
#pragma unroll
    for (int off = 32; off; off >>= 1) s += __shfl_down(s, off);
    if (lane == 0) cvec[c] = loadv(bias, f, c) - s;
}

// ---- degree histogram, packed: lo 16 = total deg, hi 16 = in-deg (max deg << 65536)
__global__ void k_hist(const int* __restrict__ rows, int E, int half,
                       int* __restrict__ deg) {
    int i = blockIdx.x * blockDim.x + threadIdx.x;
    if (i < E) atomicAdd(&deg[rows[i]], (i < half) ? 0x10001 : 1);
}

// ---- scan stage A (scans total-degree = low 16 bits of packed deg)
__global__ void k_scan_a(const int* __restrict__ deg, int N, int* __restrict__ row_start,
                         int* __restrict__ blk_sum, float* __restrict__ dinv) {
    __shared__ int s[1024];
    int t = threadIdx.x;
    int i = blockIdx.x * 1024 + t;
    int v = (i < N) ? (deg[i] & 0xFFFF) : 0;
    if (i < N) dinv[i] = v > 0 ? rsqrtf((float)v) : 0.f;
    s[t] = v;
    __syncthreads();
    for (int off = 1; off < 1024; off <<= 1) {
        int add = (t >= off) ? s[t - off] : 0;
        __syncthreads();
        s[t] += add;
        __syncthreads();
    }
    if (i < N) row_start[i] = s[t] - v;
    if (t == 1023) blk_sum[blockIdx.x] = s[1023];
}

// ---- scan stage B (nb <= 128)
__global__ void k_scan_b(int* __restrict__ blk_sum, int nb) {
    __shared__ int s[128];
    int t = threadIdx.x;
    int v = (t < nb) ? blk_sum[t] : 0;
    s[t] = v;
    __syncthreads();
    for (int off = 1; off < 128; off <<= 1) {
        int add = (t >= off) ? s[t - off] : 0;
        __syncthreads();
        s[t] += add;
        __syncthreads();
    }
    if (t < nb) blk_sum[t] = s[t] - v;
}

// ---- scan stage C: finalize row_start; seed both segment cursors
__global__ void k_scan_c(int* __restrict__ row_start, const int* __restrict__ blk_sum,
                         const int* __restrict__ degp,
                         int N, int E, int* __restrict__ cur_in, int* __restrict__ cur_out) {
    int i = blockIdx.x * 1024 + threadIdx.x;
    if (i < N) {
        int v = row_start[i] + blk_sum[blockIdx.x];
        row_start[i] = v;
        cur_in[i] = v;
        cur_out[i] = v + (int)(((unsigned)degp[i]) >> 16);
    }
    if (i == 0) row_start[N] = E;
}

// ---- fill CSR records {meta = col<<9 | et, nrm = dinv[row]*dinv[col]},
// segment-sorted (in-edges fill front of row segment, out-edges fill back)
__global__ void k_fill(const int* __restrict__ ei, const int* __restrict__ et, int E, int half,
                       int* __restrict__ cur_in, int* __restrict__ cur_out,
                       const float* __restrict__ dinv, uint2* __restrict__ csr) {
    int e = blockIdx.x * blockDim.x + threadIdx.x;
    if (e >= E) return;
    int r_ = ei[e];
    int c_ = ei[E + e];
    int t_ = et[e];
    float w = dinv[r_] * dinv[c_];
    uint32_t m = ((uint32_t)c_ << 9) | (uint32_t)t_;
    int pos = (e < half) ? atomicAdd(&cur_in[r_], 1) : atomicAdd(&cur_out[r_], 1);
    csr[pos] = make_uint2(m, __float_as_uint(w));
}

// ---- per-node pre-matmul aggregation over segment-sorted rec64 CSR.
// (at its memory-system floor per rounds 1-3: random 512B row gathers)
__global__ __launch_bounds__(256) void k_agg(
    const uint2* __restrict__ csr, const int* __restrict__ row_start,
    const int* __restrict__ degp,
    const void* __restrict__ x_raw, const uint16_t* __restrict__ x_bf,
    const uint16_t* __restrict__ r_bf, const int* __restrict__ flagp,
    uint16_t* __restrict__ s_in, uint16_t* __restrict__ s_out, int N) {
    const char* xb = (const char*)((*flagp) ? x_bf : (const uint16_t*)x_raw);
    const char* rb = (const char*)r_bf;
    int node = blockIdx.x * 4 + (threadIdx.x >> 6);
    int lane = threadIdx.x & 63;
    if (node >= N) return;
    int half = lane >> 5;
    int cob = (lane & 31) * 16;            // byte offset of this lane's 8 channels
    int s = row_start[node], e = row_start[node + 1];
    int mid = s + (int)(((unsigned)degp[node]) >> 16);

    f32x2_t ax[4], ar[4];
    float a[8];

    // ---- phase 1: in-edges [s, mid)
#pragma unroll
    for (int k = 0; k < 4; k++) { ax[k] = (f32x2_t){0.f, 0.f}; ar[k] = (f32x2_t){0.f, 0.f}; }
    for (int j = s + half; j < mid; j += 2) {
        uint2 rec = csr[j];
        uint32_t m = rec.x;
        float w = __uint_as_float(rec.y);
        uint4 xv = *(const uint4*)(xb + (m & 0xFFFFFE00u) + cob);
        uint4 rv = *(const uint4*)(rb + ((m & 511u) << 9) + cob);
        f32x2_t w2 = {w, w};
        pkfma(ax[0], up2(xv.x), w2); pkfma(ar[0], up2(rv.x), w2);
        pkfma(ax[1], up2(xv.y), w2); pkfma(ar[1], up2(rv.y), w2);
        pkfma(ax[2], up2(xv.z), w2); pkfma(ar[2], up2(rv.z), w2);
        pkfma(ax[3], up2(xv.w), w2); pkfma(ar[3], up2(rv.w), w2);
    }
#pragma unroll
    for (int k = 0; k < 4; k++) { a[2 * k] = ax[k][0] - ar[k][0]; a[2 * k + 1] = ax[k][1] - ar[k][1]; }
#pragma unroll
    for (int k = 0; k < 8; k++) a[k] += __shfl_xor(a[k], 32);
    if (half == 0) {
        uint4 o;
        o.x = pack2(a[0], a[1]); o.y = pack2(a[2], a[3]);
        o.z = pack2(a[4], a[5]); o.w = pack2(a[6], a[7]);
        *(uint4*)(s_in + (size_t)node * D_DIM + (cob >> 1)) = o;
    }

    // ---- phase 2: out-edges [mid, e)
#pragma unroll
    for (int k = 0; k < 4; k++) { ax[k] = (f32x2_t){0.f, 0.f}; ar[k] = (f32x2_t){0.f, 0.f}; }
    for (int j = mid + half; j < e; j += 2) {
        uint2 rec = csr[j];
        uint32_t m = rec.x;
        float w = __uint_as_float(rec.y);
        uint4 xv = *(const uint4*)(xb + (m & 0xFFFFFE00u) + cob);
        uint4 rv = *(const uint4*)(rb + ((m & 511u) << 9) + cob);
        f32x2_t w2 = {w, w};
        pkfma(ax[0], up2(xv.x), w2); pkfma(ar[0], up2(rv.x), w2);
        pkfma(ax[1], up2(xv.y), w2); pkfma(ar[1], up2(rv.y), w2);
        pkfma(ax[2], up2(xv.z), w2); pkfma(ar[2], up2(rv.z), w2);
        pkfma(ax[3], up2(xv.w), w2); pkfma(ar[3], up2(rv.w), w2);
    }
#pragma unroll
    for (int k = 0; k < 4; k++) { a[2 * k] = ax[k][0] - ar[k][0]; a[2 * k + 1] = ax[k][1] - ar[k][1]; }
#pragma unroll
    for (int k = 0; k < 8; k++) a[k] += __shfl_xor(a[k], 32);
    if (half == 1) {
        uint4 o;
        o.x = pack2(a[0], a[1]); o.y = pack2(a[2], a[3]);
        o.z = pack2(a[4], a[5]); o.w = pack2(a[6], a[7]);
        *(uint4*)(s_out + (size_t)node * D_DIM + (cob >> 1)) = o;
    }
}

// ---- MFMA GEMM: out[M,256] = [a0|a1|a2][M,ktot] @ bt (+ addvec)
// 512 threads = 8 waves of 64x64 tiles over a 128x256 block tile.
// DOUBLE-BUFFERED prefetch pipeline (T3/T4-minimum): stage(next) issued BEFORE
// a counted s_waitcnt vmcnt(3) -> next-tile global_load_lds stays in flight
// across the barrier and the MFMA phase. Raw s_barrier + explicit waitcnts:
//   iter: STAGE(nxt) ; vmcnt(3) ; bar ; ds_read+MFMA(cur) ; lgkmcnt(0) ; bar
// lgkmcnt(0) before bar2 closes the LDS WAR hazard (next iter overwrites nxt).
// Optional fused BN stats epilogue; optional direct dtype store (dout2).
__global__ __launch_bounds__(512) void k_gemm(
    const uint16_t* a0, const uint16_t* a1,
    const uint16_t* a2, const uint16_t* a2alt, const int* __restrict__ flagp,
    int M, const uint16_t* __restrict__ bt, int bstride, int ktot,
    const float* __restrict__ addvec, uint16_t* out,
    float* __restrict__ bn_sum, float* __restrict__ bn_sq,
    void* __restrict__ dout2, long long d_off) {
    __shared__ uint16_t As[2][128 * 32];
    __shared__ uint16_t Bs[2][256 * 32];
    int fl = *flagp;
    const uint16_t* a2s = fl ? a2 : a2alt;
    int t = threadIdx.x;
    int mbase = blockIdx.x * 128;
    int wave = t >> 6, lane = t & 63;
    int wm = (wave >> 2) * 64, wn = (wave & 3) * 64;
    int quad = lane >> 4, l15 = lane & 15;

    // staging precompute (loop-invariant): 1 A-inst + 2 B-insts per wave
    int roff = lane >> 2, cidx = lane & 3;
    int arowL = wave * 16 + roff;                     // LDS row 0..127
    int achk = cidx ^ ((arowL >> 1) & 3);
    int agrow = mbase + arowL; if (agrow > M - 1) agrow = M - 1;
    size_t aoff = (size_t)agrow * D_DIM + achk * 8;
    int awoff = (wave * 16) * 32;

    int browL0 = wave * 32 + roff;                    // LDS rows 0..255
    int browL1 = browL0 + 16;
    int bchk0 = cidx ^ ((browL0 >> 1) & 3);
    int bchk1 = cidx ^ ((browL1 >> 1) & 3);
    size_t boff0 = (size_t)browL0 * bstride + bchk0 * 8;
    size_t boff1 = (size_t)browL1 * bstride + bchk1 * 8;
    int bwoff0 = (wave * 32) * 32;
    int bwoff1 = (wave * 32 + 16) * 32;

    // fragment LDS offsets (loop-invariant, swizzled)
    int afo[4], bfo[4];
#pragma unroll
    for (int im = 0; im < 4; im++) {
        int row = wm + im * 16 + l15;
        afo[im] = row * 32 + (quad ^ ((row >> 1) & 3)) * 8;
    }
#pragma unroll
    for (int in = 0; in < 4; in++) {
        int row = wn + in * 16 + l15;
        bfo[in] = row * 32 + (quad ^ ((row >> 1) & 3)) * 8;
    }

    f32x4_t acc[4][4];
#pragma unroll
    for (int i = 0; i < 4; i++)
#pragma unroll
        for (int j = 0; j < 4; j++) acc[i][j] = (f32x4_t){0.f, 0.f, 0.f, 0.f};

    auto stage = [&](int buf, int kt) {
        const uint16_t* asec = (kt < 256) ? a0 : (kt < 512 ? a1 : a2s);
        gll16(asec + aoff + (kt & 255), &As[buf][awoff]);
        gll16(bt + boff0 + kt, &Bs[buf][bwoff0]);
        gll16(bt + boff1 + kt, &Bs[buf][bwoff1]);
    };

    stage(0, 0);
    int cur = 0;
    for (int kt = 0; kt < ktot; kt += 32) {
        if (kt + 32 < ktot) {
            stage(cur ^ 1, kt + 32);
            asm volatile("s_waitcnt vmcnt(3)" ::: "memory");
        } else {
            asm volatile("s_waitcnt vmcnt(0)" ::: "memory");
        }
        __builtin_amdgcn_sched_barrier(0);
        __builtin_amdgcn_s_barrier();
        bf16x8_t af[4], bfr[4];
#pragma unroll
        for (int im = 0; im < 4; im++) af[im] = *(const bf16x8_t*)(&As[cur][afo[im]]);
#pragma unroll
        for (int in = 0; in < 4; in++) bfr[in] = *(const bf16x8_t*)(&Bs[cur][bfo[in]]);
#pragma unroll
        for (int im = 0; im < 4; im++)
#pragma unroll
            for (int in = 0; in < 4; in++)
                acc[im][in] = __builtin_amdgcn_mfma_f32_16x16x32_bf16(af[im], bfr[in], acc[im][in], 0, 0, 0);
        asm volatile("s_waitcnt lgkmcnt(0)" ::: "memory");
        __builtin_amdgcn_sched_barrier(0);
        __builtin_amdgcn_s_barrier();
        cur ^= 1;
    }

    float s4[4] = {0.f, 0.f, 0.f, 0.f};
    float q4[4] = {0.f, 0.f, 0.f, 0.f};
#pragma unroll
    for (int im = 0; im < 4; im++) {
#pragma unroll
        for (int in = 0; in < 4; in++) {
            int gn = wn + in * 16 + l15;
            float av_ = addvec ? addvec[gn] : 0.f;
#pragma unroll
            for (int i2 = 0; i2 < 4; i2++) {
                int gm = mbase + wm + im * 16 + quad * 4 + i2;
                if (gm < M) {
                    float val = acc[im][in][i2] + av_;
                    if (dout2) {
                        size_t idx = (size_t)d_off + (size_t)gm * D_DIM + gn;
                        if (fl) ((float*)dout2)[idx] = val;
                        else    ((uint16_t*)dout2)[idx] = f2bf(val);
                    } else {
                        out[(size_t)gm * D_DIM + gn] = f2bf(val);
                    }
                    if (bn_sum) { s4[in] += val; q4[in] += val * val; }
                }
            }
        }
    }
    if (bn_sum) {
        float* sred = (float*)&As[0][0];   // reuse staging LDS (k-loop done)
        __syncthreads();
        if (t < 256) { sred[t] = 0.f; sred[t + 256] = 0.f; }
        __syncthreads();
#pragma unroll
        for (int in = 0; in < 4; in++) {
            float sv = s4[in], qv = q4[in];
            sv += __shfl_xor(sv, 16); sv += __shfl_xor(sv, 32);
            qv += __shfl_xor(qv, 16); qv += __shfl_xor(qv, 32);
            if (quad == 0) {
                int gn = wn + in * 16 + l15;
                atomicAdd(&sred[gn], sv);
                atomicAdd(&sred[gn + 256], qv);
            }
        }
        __syncthreads();
        if (t < 256) {
            atomicAdd(&bn_sum[t], sred[t]);
            atomicAdd(&bn_sq[t], sred[t + 256]);
        }
    }
}

// ---- final: BN finalize (per-block, L2-hot inputs) + normalize + tanh,
// write d_out h region in detected dtype
__global__ __launch_bounds__(256) void k_final(const uint16_t* __restrict__ h_pre,
                                               const float* __restrict__ bn_sum,
                                               const float* __restrict__ bn_sq,
                                               const void* __restrict__ gamma,
                                               const void* __restrict__ beta,
                                               const int* __restrict__ flagp,
                                               int N, void* __restrict__ dout, int total) {
    __shared__ float ssc[256], ssh[256];
    int f = *flagp;
    {
        int c = threadIdx.x;
        float inv_n = 1.f / (float)N;
        float mean = bn_sum[c] * inv_n;
        float var = bn_sq[c] * inv_n - mean * mean;
        float sc = loadv(gamma, f, c) * rsqrtf(var + 1e-5f);
        ssc[c] = sc;
        ssh[c] = loadv(beta, f, c) - mean * sc;
    }
    __syncthreads();
    int t = blockIdx.x * 256 + threadIdx.x;
    int base = t * 8;
    if (base >= total) return;
    int c0 = base & (D_DIM - 1);
    uint4 v = *(const uint4*)(h_pre + base);
    uint16_t e[8];
    e[0] = (uint16_t)(v.x & 0xFFFF); e[1] = (uint16_t)(v.x >> 16);
    e[2] = (uint16_t)(v.y & 0xFFFF); e[3] = (uint16_t)(v.y >> 16);
    e[4] = (uint16_t)(v.z & 0xFFFF); e[5] = (uint16_t)(v.z >> 16);
    e[6] = (uint16_t)(v.w & 0xFFFF); e[7] = (uint16_t)(v.w >> 16);
    float r[8];
#pragma unroll
    for (int i = 0; i < 8; i++)
        r[i] = fast_tanh(bf2f(e[i]) * ssc[c0 + i] + ssh[c0 + i]);
    if (f) {
        float* fo = (float*)dout + base;
        float4 o0 = {r[0], r[1], r[2], r[3]};
        float4 o1 = {r[4], r[5], r[6], r[7]};
        *(float4*)fo = o0;
        *(float4*)(fo + 4) = o1;
    } else {
        uint4 o;
        o.x = (uint32_t)f2bf(r[0]) | ((uint32_t)f2bf(r[1]) << 16);
        o.y = (uint32_t)f2bf(r[2]) | ((uint32_t)f2bf(r[3]) << 16);
        o.z = (uint32_t)f2bf(r[4]) | ((uint32_t)f2bf(r[5]) << 16);
        o.w = (uint32_t)f2bf(r[6]) | ((uint32_t)f2bf(r[7]) << 16);
        *(uint4*)((uint16_t*)dout + base) = o;
    }
}

extern "C" void kernel_launch(void* const* d_in, const int* in_sizes, int n_in,
                              void* d_out, int out_size, void* d_ws, size_t ws_size,
                              hipStream_t stream) {
    const void* x        = d_in[0];
    const void* r        = d_in[1];
    const void* w_in     = d_in[2];
    const void* w_out    = d_in[3];
    const void* w_loop   = d_in[4];
    const void* w_rel    = d_in[5];
    const void* loop_rel = d_in[6];
    const void* bias     = d_in[7];
    const void* bn_gamma = d_in[8];
    const void* bn_beta  = d_in[9];
    const int* edge_index = (const int*)d_in[10];
    const int* edge_type  = (const int*)d_in[11];

    const int N = in_sizes[0] / D_DIM;       // 100000
    const int R = in_sizes[1] / D_DIM;       // 474
    const int E = in_sizes[11];              // 1000000
    const int half = E / 2;

    // ---- workspace carve (~62 MB)
    char* p = (char*)d_ws;
    auto alloc = [&](size_t bytes) -> void* {
        void* q = (void*)p;
        p += (bytes + 255) & ~(size_t)255;
        return q;
    };
    uint16_t* s_out   = (uint16_t*)alloc((size_t)N * D_DIM * 2);   // also h_pre (in-place GEMM out)
    uint2*    csr     = (uint2*)alloc((size_t)E * 8);
    uint16_t* bt_big  = (uint16_t*)alloc((size_t)D_DIM * KBIG * 2);
    uint16_t* bt_rel  = (uint16_t*)alloc((size_t)D_DIM * D_DIM * 2);
    uint16_t* r_bf    = (uint16_t*)alloc((size_t)R * D_DIM * 2 + 65536); // slack for OOB-clamped rows
    int*      deg     = (int*)alloc((size_t)N * 4);   // packed: lo16 total, hi16 in-deg
    int*      rstart  = (int*)alloc((size_t)(N + 1) * 4);
    int*      cursor  = (int*)alloc((size_t)N * 4);
    int*      cursor_out = (int*)alloc((size_t)N * 4);
    float*    dinv    = (float*)alloc((size_t)N * 4);
    int*      blksum  = (int*)alloc(128 * 4);
    float*    cvec    = (float*)alloc(D_DIM * 4);
    float*    bn_sum  = (float*)alloc(D_DIM * 4);     // bn_sq contiguous after
    float*    bn_sq   = (float*)alloc(D_DIM * 4);
    int*      dflag   = (int*)alloc(256);
    (void)bn_sq;

    // s_in (bf16) lives in d_out[0 .. 51.2MB); x_bf (bf16, only when input is
    // f32) lives in d_out[51.2 .. 102.4MB) -- valid because f32 d_out h region
    // is 102.4MB. When input is bf16, x is used raw and x_bf never touched.
    uint16_t* s_in = (uint16_t*)d_out;
    uint16_t* x_bf = (uint16_t*)d_out + (size_t)N * D_DIM;
    uint16_t* h_pre = s_out;

    hipMemsetAsync(deg, 0, (size_t)N * 4, stream);
    hipMemsetAsync(bn_sum, 0, 2 * D_DIM * 4, stream);   // bn_sum + bn_sq contiguous

    k_detect<<<1, 64, 0, stream>>>((const uint32_t*)x, dflag);
    // canonical bf16 copies
    int xvec = N * D_DIM / 8;
    k_cast<<<(xvec + 255) / 256, 256, 0, stream>>>(x, x_bf, xvec, dflag, /*skip_bf=*/1);
    int rvec = R * D_DIM / 8;
    k_cast<<<(rvec + 255) / 256, 256, 0, stream>>>(r, r_bf, rvec, dflag, /*skip_bf=*/0);
    k_transpose<<<dim3(8, 8, 4), dim3(32, 32), 0, stream>>>(w_in, w_out, w_loop, w_rel,
                                                            dflag, bt_big, bt_rel);
    k_cvec<<<D_DIM, 64, 0, stream>>>(loop_rel, w_loop, bias, dflag, cvec);

    // CSR build (segment-sorted: in-edges before out-edges within each row)
    int eb = (E + 255) / 256;
    k_hist<<<eb, 256, 0, stream>>>(edge_index, E, half, deg);
    int nb = (N + 1023) / 1024;
    k_scan_a<<<nb, 1024, 0, stream>>>(deg, N, rstart, blksum, dinv);
    k_scan_b<<<1, 128, 0, stream>>>(blksum, nb);
    k_scan_c<<<nb, 1024, 0, stream>>>(rstart, blksum, deg, N, E, cursor, cursor_out);
    k_fill<<<eb, 256, 0, stream>>>(edge_index, edge_type, E, half, cursor, cursor_out,
                                   dinv, csr);

    // pre-matmul aggregation: s_in -> d_out, s_out -> ws
    k_agg<<<(N + 3) / 4, 256, 0, stream>>>(csr, rstart, deg, x, x_bf, r_bf, dflag,
                                           s_in, s_out, N);

    // h_pre = [s_in | s_out | x] @ [W_in; W_out; W_loop] + cvec (in place over
    // s_out), with fused BN sum/sumsq epilogue
    int gx = (N + 127) / 128;
    k_gemm<<<gx, 512, 0, stream>>>(s_in, s_out, x_bf, (const uint16_t*)x, dflag,
                                   N, bt_big, KBIG, KBIG, cvec, h_pre, bn_sum, bn_sq,
                                   nullptr, 0);
    // r_out = r @ w_rel, stored directly to d_out r region in detected dtype
    int gr_ = (R + 127) / 128;
    k_gemm<<<gr_, 512, 0, stream>>>(r_bf, r_bf, r_bf, r_bf, dflag,
                                    R, bt_rel, D_DIM, D_DIM, nullptr, nullptr,
                                    nullptr, nullptr,
                                    d_out, (long long)N * D_DIM);

    // BN finalize folded into k_final; normalize + tanh -> d_out (dtype per flag)
    int total = N * D_DIM;
    k_final<<<(total / 8 + 255) / 256, 256, 0, stream>>>(h_pre, bn_sum, bn_sq,
                                                         bn_gamma, bn_beta, dflag,
                                                         N, d_out, total);
}